// Round 1
// baseline (128.160 us; speedup 1.0000x reference)
//
#include <hip/hip_runtime.h>
#include <math.h>

#define N_NODES 1024
#define N_EVAL 131072
#define NUM_POLES 8
#define PI_D 3.14159265358979323846

// ws layout: double lw[1024] | float nodes_f[1024] | float w_f[1024] | float wv_f[1024]

__device__ __forceinline__ double cheb_node(int j) {
    return cos(PI_D * (double)j / (double)(N_NODES - 1));
}

// Kernel A: one block per node j; 256 threads reduce -sum log|n_j - n_i| (double).
__global__ void wk_logw(const float* __restrict__ poles_real,
                        const float* __restrict__ poles_imag,
                        double* __restrict__ lwd) {
    const int j = blockIdx.x;
    const int t = threadIdx.x;
    const double nj = cheb_node(j);
    double part = 0.0;
    for (int i = t; i < N_NODES; i += 256) {
        if (i != j) {
            part -= log(fabs(nj - cheb_node(i)));
        }
    }
    __shared__ double red[256];
    red[t] = part;
    __syncthreads();
    for (int s = 128; s > 0; s >>= 1) {
        if (t < s) red[t] += red[t + s];
        __syncthreads();
    }
    if (t == 0) {
        double lw = red[0];
        for (int m = 0; m < NUM_POLES; ++m) {
            double pr = (double)poles_real[m];
            double pim = (double)poles_imag[m];
            double dr = nj - pr;
            lw += log(dr * dr + pim * pim);
        }
        lwd[j] = lw;
    }
}

// Kernel B: single block of 1024: max-reduce log-weights, exp, emit float arrays.
// Sign is (-1)^j: nodes = cos(pi*j/1023) are strictly decreasing, so
// neg_count[j] = #(i<j) = j (matches reference's diff<0 count).
__global__ void wk_finalize(const float* __restrict__ values,
                            const double* __restrict__ lwd,
                            float* __restrict__ nodes_f,
                            float* __restrict__ w_f,
                            float* __restrict__ wv_f) {
    const int j = threadIdx.x;
    const double lw = lwd[j];
    __shared__ double red[N_NODES];
    red[j] = lw;
    __syncthreads();
    for (int s = N_NODES / 2; s > 0; s >>= 1) {
        if (j < s) red[j] = fmax(red[j], red[j + s]);
        __syncthreads();
    }
    const double mx = red[0];
    double w = exp(lw - mx);
    if (j & 1) w = -w;
    const float wf = (float)w;
    nodes_f[j] = (float)cheb_node(j);
    w_f[j] = wf;
    wv_f[j] = wf * values[j];
}

// Eval kernel: 1 point/thread, nodes/weights staged in LDS, float4 LDS reads
// (all lanes read the same address -> broadcast, no bank conflicts).
__global__ __launch_bounds__(256) void eval_kernel(
    const float* __restrict__ x_eval,
    const float* __restrict__ nodes_f,
    const float* __restrict__ w_f,
    const float* __restrict__ wv_f,
    float* __restrict__ out) {
    __shared__ __align__(16) float s_n[N_NODES];
    __shared__ __align__(16) float s_w[N_NODES];
    __shared__ __align__(16) float s_v[N_NODES];
    const int t = threadIdx.x;
    for (int k = t; k < N_NODES; k += 256) {
        s_n[k] = nodes_f[k];
        s_w[k] = w_f[k];
        s_v[k] = wv_f[k];
    }
    __syncthreads();

    const int i = blockIdx.x * 256 + t;
    const float x = x_eval[i];

    float num = 0.0f, den = 0.0f;
    float hnum = 0.0f, hden = 0.0f;
    bool hit = false;

    const float4* n4 = (const float4*)s_n;
    const float4* w4 = (const float4*)s_w;
    const float4* v4 = (const float4*)s_v;

#define BODY(C)                                                            \
    {                                                                      \
        float d = x - an.C;                                                \
        if (__builtin_expect(fabsf(d) < 1e-14f, 0)) {                      \
            hit = true; hnum += av.C; hden += aw.C;                        \
        } else {                                                           \
            float r = __builtin_amdgcn_rcpf(d);                            \
            r = fmaf(r, fmaf(-d, r, 1.0f), r); /* 1 Newton step */         \
            num = fmaf(av.C, r, num);                                      \
            den = fmaf(aw.C, r, den);                                      \
        }                                                                  \
    }

#pragma unroll 4
    for (int j4 = 0; j4 < N_NODES / 4; ++j4) {
        float4 an = n4[j4];
        float4 aw = w4[j4];
        float4 av = v4[j4];
        BODY(x) BODY(y) BODY(z) BODY(w)
    }
#undef BODY

    out[i] = hit ? (hnum / hden) : (num / den);
}

extern "C" void kernel_launch(void* const* d_in, const int* in_sizes, int n_in,
                              void* d_out, int out_size, void* d_ws, size_t ws_size,
                              hipStream_t stream) {
    const float* x_eval     = (const float*)d_in[0];
    const float* values     = (const float*)d_in[1];
    const float* poles_real = (const float*)d_in[2];
    const float* poles_imag = (const float*)d_in[3];
    float* out = (float*)d_out;

    double* lwd    = (double*)d_ws;
    float* nodes_f = (float*)(lwd + N_NODES);
    float* w_f     = nodes_f + N_NODES;
    float* wv_f    = w_f + N_NODES;

    wk_logw<<<N_NODES, 256, 0, stream>>>(poles_real, poles_imag, lwd);
    wk_finalize<<<1, N_NODES, 0, stream>>>(values, lwd, nodes_f, w_f, wv_f);
    eval_kernel<<<N_EVAL / 256, 256, 0, stream>>>(x_eval, nodes_f, w_f, wv_f, out);
}